// Round 1
// baseline (48.123 us; speedup 1.0000x reference)
//
#include <hip/hip_runtime.h>

// Problem: y[b,o] = sum_i w[o,i] * (g-1) * exp(-0.5*g^2),  g = s[o,i]*(x[b,i]+c[o,i])
// then BatchNorm over batch axis (training stats, biased var).
// B=2048, I=256, O=256, all fp32.

#define BATCH 2048
#define IFEAT 256
#define OFEAT 256

#define BT 64   // batch tile per block
#define OT 32   // out-feature tile per block
#define IC 64   // i chunk staged in LDS
#define LDP 68  // padded LDS row stride (floats): 68*4B = 272B, 16B aligned, breaks bank aliasing

#define KLOG2E (-0.7213475204444817f)  // -0.5 * log2(e)

__device__ __forceinline__ float chain4(const float4 s, const float4 c, const float4 w,
                                        const float4 xv, float acc) {
    {
        float g = __builtin_fmaf(s.x, xv.x, c.x);
        float e = __builtin_amdgcn_exp2f(KLOG2E * g * g);
        acc = __builtin_fmaf(w.x * e, g - 1.0f, acc);
    }
    {
        float g = __builtin_fmaf(s.y, xv.y, c.y);
        float e = __builtin_amdgcn_exp2f(KLOG2E * g * g);
        acc = __builtin_fmaf(w.y * e, g - 1.0f, acc);
    }
    {
        float g = __builtin_fmaf(s.z, xv.z, c.z);
        float e = __builtin_amdgcn_exp2f(KLOG2E * g * g);
        acc = __builtin_fmaf(w.z * e, g - 1.0f, acc);
    }
    {
        float g = __builtin_fmaf(s.w, xv.w, c.w);
        float e = __builtin_amdgcn_exp2f(KLOG2E * g * g);
        acc = __builtin_fmaf(w.w * e, g - 1.0f, acc);
    }
    return acc;
}

__global__ __launch_bounds__(256) void xmm_main(
    const float* __restrict__ x, const float* __restrict__ scale,
    const float* __restrict__ bias, const float* __restrict__ weight,
    float* __restrict__ y, float* __restrict__ psum, float* __restrict__ psqr)
{
    __shared__ float xs[BT * LDP];       // x tile   [64][68]
    __shared__ float ss[OT * LDP];       // scale    [32][68]
    __shared__ float cs[OT * LDP];       // scale*bias
    __shared__ float wl[OT * LDP];       // weight
    __shared__ float red_s[4][OT];
    __shared__ float red_q[4][OT];

    const int t  = threadIdx.x;
    const int to = t & 15;    // o-lane (coalesced writes)
    const int tw = t >> 4;    // b-group (0..15), 4 rows each
    const int o0 = blockIdx.x * OT;
    const int b0 = blockIdx.y * BT;

    float acc[4][2];
#pragma unroll
    for (int j = 0; j < 4; ++j) { acc[j][0] = 0.0f; acc[j][1] = 0.0f; }

    for (int c = 0; c < IFEAT / IC; ++c) {
        const int i0 = c * IC;
        __syncthreads();
        // ---- stage x tile: 64 rows x 64 floats ----
#pragma unroll
        for (int k = 0; k < 4; ++k) {
            int flat = t + k * 256;
            int row = flat >> 4, c4 = flat & 15;
            float4 v = *(const float4*)(x + (b0 + row) * IFEAT + i0 + c4 * 4);
            *(float4*)(xs + row * LDP + c4 * 4) = v;
        }
        // ---- stage params: 32 rows x 64 floats x 3, fold c := s*bias ----
#pragma unroll
        for (int k = 0; k < 2; ++k) {
            int flat = t + k * 256;
            int orow = flat >> 4, c4 = flat & 15;
            const int gidx = (o0 + orow) * IFEAT + i0 + c4 * 4;
            float4 s4 = *(const float4*)(scale + gidx);
            float4 b4 = *(const float4*)(bias + gidx);
            float4 w4 = *(const float4*)(weight + gidx);
            float4 sc;
            sc.x = s4.x * b4.x; sc.y = s4.y * b4.y;
            sc.z = s4.z * b4.z; sc.w = s4.w * b4.w;
            *(float4*)(ss + orow * LDP + c4 * 4) = s4;
            *(float4*)(cs + orow * LDP + c4 * 4) = sc;
            *(float4*)(wl + orow * LDP + c4 * 4) = w4;
        }
        __syncthreads();

#pragma unroll 2
        for (int ii = 0; ii < IC / 4; ++ii) {
            float4 sA = *(const float4*)(ss + to * LDP + ii * 4);
            float4 cA = *(const float4*)(cs + to * LDP + ii * 4);
            float4 wA = *(const float4*)(wl + to * LDP + ii * 4);
            float4 sB = *(const float4*)(ss + (to + 16) * LDP + ii * 4);
            float4 cB = *(const float4*)(cs + (to + 16) * LDP + ii * 4);
            float4 wB = *(const float4*)(wl + (to + 16) * LDP + ii * 4);
#pragma unroll
            for (int j = 0; j < 4; ++j) {
                float4 xv = *(const float4*)(xs + (tw * 4 + j) * LDP + ii * 4);
                acc[j][0] = chain4(sA, cA, wA, xv, acc[j][0]);
                acc[j][1] = chain4(sB, cB, wB, xv, acc[j][1]);
            }
        }
    }

    // ---- write Y (pre-BN) ----
#pragma unroll
    for (int j = 0; j < 4; ++j) {
        const int b = b0 + tw * 4 + j;
        y[b * OFEAT + o0 + to]      = acc[j][0];
        y[b * OFEAT + o0 + to + 16] = acc[j][1];
    }

    // ---- per-block partial sums over the 64 batch rows, per o ----
    float s0 = acc[0][0] + acc[1][0] + acc[2][0] + acc[3][0];
    float s1 = acc[0][1] + acc[1][1] + acc[2][1] + acc[3][1];
    float q0 = acc[0][0]*acc[0][0] + acc[1][0]*acc[1][0] + acc[2][0]*acc[2][0] + acc[3][0]*acc[3][0];
    float q1 = acc[0][1]*acc[0][1] + acc[1][1]*acc[1][1] + acc[2][1]*acc[2][1] + acc[3][1]*acc[3][1];
#pragma unroll
    for (int mask = 16; mask <= 32; mask <<= 1) {
        s0 += __shfl_xor(s0, mask);
        s1 += __shfl_xor(s1, mask);
        q0 += __shfl_xor(q0, mask);
        q1 += __shfl_xor(q1, mask);
    }
    if ((t & 48) == 0) {                 // one rep lane per (wave, to)
        const int w = t >> 6;
        red_s[w][to]      = s0;  red_s[w][to + 16] = s1;
        red_q[w][to]      = q0;  red_q[w][to + 16] = q1;
    }
    __syncthreads();
    if (t < OT) {
        float s = red_s[0][t] + red_s[1][t] + red_s[2][t] + red_s[3][t];
        float q = red_q[0][t] + red_q[1][t] + red_q[2][t] + red_q[3][t];
        psum[blockIdx.y * OFEAT + o0 + t] = s;
        psqr[blockIdx.y * OFEAT + o0 + t] = q;
    }
}

__global__ __launch_bounds__(256) void bn_stats(
    const float* __restrict__ psum, const float* __restrict__ psqr,
    float* __restrict__ mean, float* __restrict__ rstd)
{
    const int o = threadIdx.x;
    float s = 0.0f, q = 0.0f;
#pragma unroll 4
    for (int bg = 0; bg < BATCH / BT; ++bg) {
        s += psum[bg * OFEAT + o];
        q += psqr[bg * OFEAT + o];
    }
    const float m = s * (1.0f / (float)BATCH);
    const float v = q * (1.0f / (float)BATCH) - m * m;
    mean[o] = m;
    rstd[o] = rsqrtf(v + 1e-5f);
}

__global__ __launch_bounds__(256) void bn_apply(
    float* __restrict__ y, const float* __restrict__ mean, const float* __restrict__ rstd,
    const float* __restrict__ gamma, const float* __restrict__ beta)
{
    const int i4 = blockIdx.x * 256 + threadIdx.x;   // over 131072 float4s
    const int o4 = i4 & (OFEAT / 4 - 1);
    float4 yv = ((float4*)y)[i4];
    const float4 m  = ((const float4*)mean)[o4];
    const float4 r  = ((const float4*)rstd)[o4];
    const float4 g  = ((const float4*)gamma)[o4];
    const float4 be = ((const float4*)beta)[o4];
    yv.x = __builtin_fmaf(g.x * (yv.x - m.x), r.x, be.x);
    yv.y = __builtin_fmaf(g.y * (yv.y - m.y), r.y, be.y);
    yv.z = __builtin_fmaf(g.z * (yv.z - m.z), r.z, be.z);
    yv.w = __builtin_fmaf(g.w * (yv.w - m.w), r.w, be.w);
    ((float4*)y)[i4] = yv;
}

extern "C" void kernel_launch(void* const* d_in, const int* in_sizes, int n_in,
                              void* d_out, int out_size, void* d_ws, size_t ws_size,
                              hipStream_t stream) {
    const float* x      = (const float*)d_in[0];
    const float* scale  = (const float*)d_in[1];
    const float* bias   = (const float*)d_in[2];
    const float* weight = (const float*)d_in[3];
    const float* gamma  = (const float*)d_in[4];
    const float* beta   = (const float*)d_in[5];
    float* y  = (float*)d_out;
    float* ws = (float*)d_ws;

    float* psum = ws;            // 32*256
    float* psqr = ws + 8192;     // 32*256
    float* mean = ws + 16384;    // 256
    float* rstd = ws + 16640;    // 256

    xmm_main<<<dim3(OFEAT / OT, BATCH / BT), 256, 0, stream>>>(x, scale, bias, weight, y, psum, psqr);
    bn_stats<<<1, 256, 0, stream>>>(psum, psqr, mean, rstd);
    bn_apply<<<(BATCH * OFEAT / 4) / 256, 256, 0, stream>>>(y, mean, rstd, gamma, beta);
}